// Round 2
// baseline (682.744 us; speedup 1.0000x reference)
//
#include <hip/hip_runtime.h>

#define NT 512
#define SEQ_LEN 8192

static __device__ __forceinline__ float2 f2(float x, float y){ return make_float2(x,y); }
static __device__ __forceinline__ float2 cadd(float2 a, float2 b){ return f2(a.x+b.x, a.y+b.y); }
static __device__ __forceinline__ float2 csub(float2 a, float2 b){ return f2(a.x-b.x, a.y-b.y); }
static __device__ __forceinline__ float2 cmul(float2 a, float2 b){ return f2(a.x*b.x-a.y*b.y, a.x*b.y+a.y*b.x); }
static __device__ __forceinline__ float2 cmulc(float2 a, float2 b){ return f2(a.x*b.x+a.y*b.y, a.y*b.x-a.x*b.y); } // a*conj(b)
static __device__ __forceinline__ float2 mul_mi(float2 a){ return f2(a.y, -a.x); } // a * (-i)
static __device__ __forceinline__ int swz(int e){ return e ^ ((e>>4)&15) ^ ((e>>8)&15); }
static __device__ __forceinline__ int rev13(int v){ return (int)(__brev((unsigned)v) >> 19); }

// ---------------- MLP: h3[j][16] = sin-MLP(z[j]) ----------------
__global__ void hyena_mlp(const float* __restrict__ z,
                          const float* __restrict__ W1, const float* __restrict__ b1,
                          const float* __restrict__ W2, const float* __restrict__ b2,
                          const float* __restrict__ W3, const float* __restrict__ b3,
                          const float* __restrict__ freq,
                          float* __restrict__ h3) {
    int j = blockIdx.x * blockDim.x + threadIdx.x;
    if (j >= SEQ_LEN) return;
    float z0 = z[3*j+0], z1 = z[3*j+1], z2 = z[3*j+2];
    float ha[16], hb[16];
#pragma unroll
    for (int o = 0; o < 16; ++o) {
        float acc = b1[o] + z0*W1[o] + z1*W1[16+o] + z2*W1[32+o];
        ha[o] = sinf(freq[o] * acc);
    }
#pragma unroll
    for (int p = 0; p < 16; ++p) {
        float acc = b2[p];
#pragma unroll
        for (int o = 0; o < 16; ++o) acc += ha[o] * W2[o*16+p];
        hb[p] = sinf(freq[p] * acc);
    }
#pragma unroll
    for (int q = 0; q < 16; ++q) {
        float acc = b3[q];
#pragma unroll
        for (int o = 0; o < 16; ++o) acc += hb[o] * W3[o*16+q];
        h3[j*16+q] = sinf(freq[q] * acc);
    }
}

// ---------------- 4-stage (radix-16-as-radix-2^4) register butterflies ----------------
struct TwSet { float2 t[8]; float2 u[4]; float2 v0, v1, wa; };
static __device__ __forceinline__ TwSet mktw(float2 wd){
    TwSet S;
    const float C1x=0.9238795325112867f, C1y=-0.3826834323650898f;  // e^{-i pi/8}
    const float C2x=0.7071067811865476f, C2y=-0.7071067811865476f;  // e^{-i pi/4}
    const float C3x=0.3826834323650898f, C3y=-0.9238795325112867f;  // e^{-i 3pi/8}
    float2 wc = cmul(wd,wd), wb = cmul(wc,wc);
    S.wa = cmul(wb,wb);
    S.t[0]=wd;
    S.t[1]=f2(wd.x*C1x-wd.y*C1y, wd.x*C1y+wd.y*C1x);
    S.t[2]=f2(wd.x*C2x-wd.y*C2y, wd.x*C2y+wd.y*C2x);
    S.t[3]=f2(wd.x*C3x-wd.y*C3y, wd.x*C3y+wd.y*C3x);
    S.t[4]=mul_mi(S.t[0]); S.t[5]=mul_mi(S.t[1]); S.t[6]=mul_mi(S.t[2]); S.t[7]=mul_mi(S.t[3]);
    S.u[0]=wc;
    S.u[1]=f2(wc.x*C2x-wc.y*C2y, wc.x*C2y+wc.y*C2x);
    S.u[2]=mul_mi(S.u[0]); S.u[3]=mul_mi(S.u[1]);
    S.v0=wb; S.v1=mul_mi(wb);
    return S;
}
// DIF (forward), stages m_lo+3 .. m_lo descending; r[k] = c[base + k*2^m_lo]
static __device__ __forceinline__ void dif4(float2 r[16], float2 wd){
    TwSet S = mktw(wd);
#pragma unroll
    for(int k=0;k<8;++k){ float2 u=r[k], v=r[k+8]; r[k]=cadd(u,v); r[k+8]=cmul(csub(u,v), S.t[k]); }
#pragma unroll
    for(int b=0;b<16;b+=8)
#pragma unroll
      for(int k=0;k<4;++k){ float2 u=r[b+k], v=r[b+k+4]; r[b+k]=cadd(u,v); r[b+k+4]=cmul(csub(u,v), S.u[k]); }
#pragma unroll
    for(int b=0;b<16;b+=4){
        { float2 u=r[b],   v=r[b+2]; r[b]  =cadd(u,v); r[b+2]=cmul(csub(u,v), S.v0); }
        { float2 u=r[b+1], v=r[b+3]; r[b+1]=cadd(u,v); r[b+3]=cmul(csub(u,v), S.v1); }
    }
#pragma unroll
    for(int b=0;b<16;b+=2){ float2 u=r[b], v=r[b+1]; r[b]=cadd(u,v); r[b+1]=cmul(csub(u,v), S.wa); }
}
// DIT (inverse), stages m_lo .. m_lo+3 ascending, conjugated twiddles
static __device__ __forceinline__ void dit4(float2 r[16], float2 wd){
    TwSet S = mktw(wd);
#pragma unroll
    for(int b=0;b<16;b+=2){ float2 u=r[b]; float2 t=cmulc(r[b+1], S.wa); r[b]=cadd(u,t); r[b+1]=csub(u,t); }
#pragma unroll
    for(int b=0;b<16;b+=4){
        { float2 u=r[b];   float2 t=cmulc(r[b+2], S.v0); r[b]  =cadd(u,t); r[b+2]=csub(u,t); }
        { float2 u=r[b+1]; float2 t=cmulc(r[b+3], S.v1); r[b+1]=cadd(u,t); r[b+3]=csub(u,t); }
    }
#pragma unroll
    for(int b=0;b<16;b+=8)
#pragma unroll
      for(int k=0;k<4;++k){ float2 u=r[b+k]; float2 t=cmulc(r[b+k+4], S.u[k]); r[b+k]=cadd(u,t); r[b+k+4]=csub(u,t); }
#pragma unroll
    for(int k=0;k<8;++k){ float2 u=r[k]; float2 t=cmulc(r[k+8], S.t[k]); r[k]=cadd(u,t); r[k+8]=csub(u,t); }
}

// aligned pair access (positions p even; swz may flip parity, so select)
static __device__ __forceinline__ void readpair(const float2* cv, int p, float2& e0, float2& e1){
    int sp = swz(p);
    float4 q = *(const float4*)&cv[sp & ~1];
    float2 lo = f2(q.x,q.y), hi = f2(q.z,q.w);
    if (sp & 1) { e0 = hi; e1 = lo; } else { e0 = lo; e1 = hi; }
}
static __device__ __forceinline__ void writepair(float2* cv, int p, float2 e0, float2 e1){
    int sp = swz(p);
    float4 q;
    if (sp & 1) q = make_float4(e1.x,e1.y,e0.x,e0.y);
    else        q = make_float4(e0.x,e0.y,e1.x,e1.y);
    *(float4*)&cv[sp & ~1] = q;
}

static __device__ __forceinline__ float2 getw(const float2* T1, const float2* T2, int k){
    return cmul(T1[k>>6], T2[k&63]);   // e^{-i pi k / 8192}
}
// rfft unpack K[k], K[8192-k] packed as float4 (scaled by 1/16384, +bias*s on real parts)
static __device__ __forceinline__ float4 kpack(float2 Ck, float2 Cm, float2 w, float bds){
    const float s = 1.0f/16384.0f;
    float2 A  = f2(0.5f*(Ck.x+Cm.x), 0.5f*(Ck.y-Cm.y));
    float2 Bc = f2(0.5f*(Ck.x-Cm.x), 0.5f*(Ck.y+Cm.y));
    float2 B  = f2(Bc.y, -Bc.x);
    float2 wB = cmul(w, B);
    return make_float4((A.x+wB.x)*s + bds, (A.y+wB.y)*s,
                       (A.x-wB.x)*s + bds, -((A.y-wB.y)*s));
}
// unpack X via w, multiply with packed K, repack into C'[k], C'[8192-k]
static __device__ __forceinline__ void pwmul(float2 Ck, float2 Cm, float4 Kp, float2 w,
                                             float2& Dk, float2& Dm){
    float2 A  = f2(0.5f*(Ck.x+Cm.x), 0.5f*(Ck.y-Cm.y));
    float2 Bc = f2(0.5f*(Ck.x-Cm.x), 0.5f*(Ck.y+Cm.y));
    float2 B  = f2(Bc.y, -Bc.x);
    float2 wB = cmul(w, B);
    float2 Xk = f2(A.x+wB.x, A.y+wB.y);
    float2 Xm = f2(A.x-wB.x, -(A.y-wB.y));
    float2 Yk = cmul(Xk, f2(Kp.x,Kp.y));
    float2 Ym = cmul(Xm, f2(Kp.z,Kp.w));
    float2 A2 = f2(Yk.x+Ym.x, Yk.y-Ym.y);
    float2 Bt = f2(Yk.x-Ym.x, Yk.y+Ym.y);
    float2 B2 = cmulc(Bt, w);
    Dk = f2(A2.x - B2.y, A2.y + B2.x);
    Dm = f2(A2.x + B2.y, B2.x - A2.y);
}

// LDS: cv 8192 f2 | tab 512 | T1 64 | T2 64  = 8832 f2 = 70656 B  -> 2 blocks/CU
#define SMEM_BYTES (8832 * 8)

__global__ __launch_bounds__(NT, 4)
void hyena_conv(const float* __restrict__ h3g, const float* __restrict__ Wout,
                const float* __restrict__ x, const float* __restrict__ bias,
                float* __restrict__ out) {
    extern __shared__ float4 smem4[];
    float2* cv  = (float2*)smem4;       // 8192
    float2* tab = cv + 8192;            // 512: W_8192^p
    float2* T1  = tab + 512;            // 64:  e^{-i pi h/128}
    float2* T2  = T1 + 64;              // 64:  e^{-i pi l/8192}
    const int t = threadIdx.x;
    const int d = blockIdx.x;
    const float PI = 3.14159265358979323846f;

    { float s_,c_; sincosf((PI/4096.0f)*(float)t, &s_, &c_); tab[t] = f2(c_, -s_); }
    if (t < 64)       { float s_,c_; sincosf((PI/128.0f)*(float)t, &s_,&c_); T1[t] = f2(c_,-s_); }
    else if (t < 128) { int l=t-64; float s_,c_; sincosf((PI/8192.0f)*(float)l,&s_,&c_); T2[l] = f2(c_,-s_); }
    __syncthreads();

    const float2 wd1 = tab[t];            // pass stride 512 (stages 12..9 / 9..12)
    const float2 wd2 = tab[(t&31)<<4];    // pass stride 32  (stages 8..5 / 5..8)
    const float2 wd3 = tab[(t&1)<<8];     // pass stride 2   (stages 4..1 / 1..4)
    const int b2 = ((t>>5)<<9) | (t&31);
    const int b3 = ((t>>1)<<5) | (t&1);

    // ---- filter row k_d -> spectrum K (kept in registers), bias folded in ----
    const float dmin = -3.0701134573253941f;   // log(0.01)/1.5
    const float dmax = -15.350567286626971f;   // log(0.01)/0.3
    const float absd = fabsf(dmin + (dmax - dmin) * ((float)d * (1.0f/1023.0f)));
    const float bds = bias[d] * (1.0f/16384.0f);
    float wcol[16];
#pragma unroll
    for (int o = 0; o < 16; ++o) wcol[o] = Wout[o*1024 + d];

    float2 r[16];
#pragma unroll
    for (int k = 0; k < 8; ++k) {
        int e = t + 512*k;                      // packed complex idx; samples 2e, 2e+1
        const float* h0 = h3g + (size_t)(2*e)*16;
        float a0 = 0.f, a1 = 0.f;
#pragma unroll
        for (int o = 0; o < 16; ++o) a0 += h0[o]    * wcol[o];
#pragma unroll
        for (int o = 0; o < 16; ++o) a1 += h0[16+o] * wcol[o];
        float ta = (float)(2*e)   * (1.0f/8191.0f);
        float tb = (float)(2*e+1) * (1.0f/8191.0f);
        r[k] = f2(a0 * __expf(-ta*absd), a1 * __expf(-tb*absd));
    }
#pragma unroll
    for (int k = 8; k < 16; ++k) r[k] = f2(0.f, 0.f);

    dif4(r, wd1);
#pragma unroll
    for (int k = 0; k < 16; ++k) cv[swz(t + 512*k)] = r[k];
    __syncthreads();
#pragma unroll
    for (int k = 0; k < 16; ++k) r[k] = cv[swz(b2 + 32*k)];
    dif4(r, wd2);
#pragma unroll
    for (int k = 0; k < 16; ++k) cv[swz(b2 + 32*k)] = r[k];
    __syncthreads();
#pragma unroll
    for (int k = 0; k < 16; ++k) r[k] = cv[swz(b3 + 2*k)];
    dif4(r, wd3);
#pragma unroll
    for (int k = 0; k < 16; ++k) cv[swz(b3 + 2*k)] = r[k];
    __syncthreads();

    float4 Ka[4], Kb[4];
    float4 K20 = make_float4(0.f,0.f,0.f,0.f);
#pragma unroll
    for (int q = 0; q < 4; ++q) {
        int f = t + 512*q;
        if (f == 0) {
            float2 a0,a1; readpair(cv, 0, a0, a1);
            float2 C0 = cadd(a0,a1), C4 = csub(a0,a1);   // fwd stage 0
            const float s = 1.0f/16384.0f;
            Ka[q] = make_float4((C0.x+C0.y)*s + bds, (C0.x-C0.y)*s + bds, C4.x*s + bds, -C4.y*s);
            Kb[q] = make_float4(0.f,0.f,0.f,0.f);
        } else {
            int g = 4096 - f;
            float2 a0,a1,b0,b1;
            readpair(cv, rev13(f), a0, a1);
            readpair(cv, rev13(g), b0, b1);
            float2 Cf=cadd(a0,a1), Cf4=csub(a0,a1), Cg=cadd(b0,b1), Cg4=csub(b0,b1);
            Ka[q] = kpack(Cf, Cg4, getw(T1,T2,f), bds);
            Kb[q] = kpack(Cg, Cf4, getw(T1,T2,g), bds);
        }
    }
    if (t == 0) {
        float2 b0,b1; readpair(cv, 2, b0, b1);   // rev13(2048) = 2
        K20 = kpack(cadd(b0,b1), csub(b0,b1), getw(T1,T2,2048), bds);
    }
    __syncthreads();

    // ---- batches ----
    for (int b = 0; b < 4; ++b) {
        const float2* xr = (const float2*)(x + ((size_t)b*1024 + d)*SEQ_LEN);
        float2* yr = (float2*)(out + ((size_t)b*1024 + d)*SEQ_LEN);

        // F1: global -> regs, stages 12..9, -> LDS
#pragma unroll
        for (int k = 0; k < 8; ++k) r[k] = xr[t + 512*k];
#pragma unroll
        for (int k = 8; k < 16; ++k) r[k] = f2(0.f,0.f);
        dif4(r, wd1);
#pragma unroll
        for (int k = 0; k < 16; ++k) cv[swz(t + 512*k)] = r[k];
        __syncthreads();
        // F2: stages 8..5
#pragma unroll
        for (int k = 0; k < 16; ++k) r[k] = cv[swz(b2 + 32*k)];
        dif4(r, wd2);
#pragma unroll
        for (int k = 0; k < 16; ++k) cv[swz(b2 + 32*k)] = r[k];
        __syncthreads();
        // F3: stages 4..1
#pragma unroll
        for (int k = 0; k < 16; ++k) r[k] = cv[swz(b3 + 2*k)];
        dif4(r, wd3);
#pragma unroll
        for (int k = 0; k < 16; ++k) cv[swz(b3 + 2*k)] = r[k];
        __syncthreads();

        // FUSED: fwd stage 0 + rfft-unpack * K + repack + inv stage 0
#pragma unroll
        for (int q = 0; q < 4; ++q) {
            int f = t + 512*q;
            if (f == 0) {
                float2 a0,a1; readpair(cv, 0, a0, a1);
                float2 C0 = cadd(a0,a1), C4 = csub(a0,a1);
                float R0 = C0.x + C0.y, RN = C0.x - C0.y;
                float Y0 = R0 * Ka[0].x, YN = RN * Ka[0].y;
                float2 D0 = f2(Y0+YN, Y0-YN);
                float2 Y4 = cmul(f2(C4.x,-C4.y), f2(Ka[0].z, Ka[0].w));
                float2 D4 = f2(2.f*Y4.x, -2.f*Y4.y);
                writepair(cv, 0, cadd(D0,D4), csub(D0,D4));
            } else {
                int g = 4096 - f;
                int p1 = rev13(f), p2 = rev13(g);
                float2 a0,a1,b0,b1;
                readpair(cv, p1, a0, a1);
                readpair(cv, p2, b0, b1);
                float2 Cf=cadd(a0,a1), Cf4=csub(a0,a1), Cg=cadd(b0,b1), Cg4=csub(b0,b1);
                float2 Df,Dg4,Dg,Df4;
                pwmul(Cf, Cg4, Ka[q], getw(T1,T2,f), Df, Dg4);
                pwmul(Cg, Cf4, Kb[q], getw(T1,T2,g), Dg, Df4);
                writepair(cv, p1, cadd(Df,Df4), csub(Df,Df4));
                writepair(cv, p2, cadd(Dg,Dg4), csub(Dg,Dg4));
            }
        }
        if (t == 0) {   // f = 2048 self-paired quad at positions (2,3)
            float2 b0,b1; readpair(cv, 2, b0, b1);
            float2 Ck=cadd(b0,b1), Cm=csub(b0,b1), Dk, Dm;
            pwmul(Ck, Cm, K20, getw(T1,T2,2048), Dk, Dm);
            writepair(cv, 2, cadd(Dk,Dm), csub(Dk,Dm));
        }
        __syncthreads();

        // I2: stages 1..4
#pragma unroll
        for (int k = 0; k < 16; ++k) r[k] = cv[swz(b3 + 2*k)];
        dit4(r, wd3);
#pragma unroll
        for (int k = 0; k < 16; ++k) cv[swz(b3 + 2*k)] = r[k];
        __syncthreads();
        // I3: stages 5..8
#pragma unroll
        for (int k = 0; k < 16; ++k) r[k] = cv[swz(b2 + 32*k)];
        dit4(r, wd2);
#pragma unroll
        for (int k = 0; k < 16; ++k) cv[swz(b2 + 32*k)] = r[k];
        __syncthreads();
        // I4: stages 9..12, write first half straight to global (bias folded into K)
#pragma unroll
        for (int k = 0; k < 16; ++k) r[k] = cv[swz(t + 512*k)];
        dit4(r, wd1);
#pragma unroll
        for (int k = 0; k < 8; ++k) yr[t + 512*k] = r[k];
        __syncthreads();
    }
}

extern "C" void kernel_launch(void* const* d_in, const int* in_sizes, int n_in,
                              void* d_out, int out_size, void* d_ws, size_t ws_size,
                              hipStream_t stream) {
    const float* x    = (const float*)d_in[0];
    const float* z    = (const float*)d_in[2];
    const float* W1   = (const float*)d_in[3];
    const float* b1   = (const float*)d_in[4];
    const float* W2   = (const float*)d_in[5];
    const float* b2   = (const float*)d_in[6];
    const float* W3   = (const float*)d_in[7];
    const float* b3   = (const float*)d_in[8];
    const float* Wout = (const float*)d_in[9];
    const float* freq = (const float*)d_in[10];
    const float* bias = (const float*)d_in[11];
    float* out = (float*)d_out;
    float* h3  = (float*)d_ws;   // 8192*16 floats = 512 KB

    hipLaunchKernelGGL(hyena_mlp, dim3(SEQ_LEN/256), dim3(256), 0, stream,
                       z, W1, b1, W2, b2, W3, b3, freq, h3);

    static bool attr_set = false;
    if (!attr_set) {
        (void)hipFuncSetAttribute((const void*)hyena_conv,
                                  hipFuncAttributeMaxDynamicSharedMemorySize,
                                  SMEM_BYTES);
        attr_set = true;
    }
    hipLaunchKernelGGL(hyena_conv, dim3(1024), dim3(NT), SMEM_BYTES, stream,
                       h3, Wout, x, bias, out);
}

// Round 3
// 414.220 us; speedup vs baseline: 1.6483x; 1.6483x over previous
//
#include <hip/hip_runtime.h>

#define NT 512
#define SEQ_LEN 8192

static __device__ __forceinline__ float2 f2(float x, float y){ return make_float2(x,y); }
static __device__ __forceinline__ float2 cadd(float2 a, float2 b){ return f2(a.x+b.x, a.y+b.y); }
static __device__ __forceinline__ float2 csub(float2 a, float2 b){ return f2(a.x-b.x, a.y-b.y); }
static __device__ __forceinline__ float2 cmul(float2 a, float2 b){ return f2(a.x*b.x-a.y*b.y, a.x*b.y+a.y*b.x); }
static __device__ __forceinline__ float2 cmulc(float2 a, float2 b){ return f2(a.x*b.x+a.y*b.y, a.y*b.x-a.x*b.y); } // a*conj(b)
static __device__ __forceinline__ float2 mul_mi(float2 a){ return f2(a.y, -a.x); } // a * (-i)
static __device__ __forceinline__ int swz(int e){ return e ^ ((e>>4)&15) ^ ((e>>8)&15); }
static __device__ __forceinline__ int rev13(int v){ return (int)(__brev((unsigned)v) >> 19); }

// ---------------- MLP: h3[j][16] = sin-MLP(z[j]) ----------------
__global__ void hyena_mlp(const float* __restrict__ z,
                          const float* __restrict__ W1, const float* __restrict__ b1,
                          const float* __restrict__ W2, const float* __restrict__ b2,
                          const float* __restrict__ W3, const float* __restrict__ b3,
                          const float* __restrict__ freq,
                          float* __restrict__ h3) {
    int j = blockIdx.x * blockDim.x + threadIdx.x;
    if (j >= SEQ_LEN) return;
    float z0 = z[3*j+0], z1 = z[3*j+1], z2 = z[3*j+2];
    float ha[16], hb[16];
#pragma unroll
    for (int o = 0; o < 16; ++o) {
        float acc = b1[o] + z0*W1[o] + z1*W1[16+o] + z2*W1[32+o];
        ha[o] = sinf(freq[o] * acc);
    }
#pragma unroll
    for (int p = 0; p < 16; ++p) {
        float acc = b2[p];
#pragma unroll
        for (int o = 0; o < 16; ++o) acc += ha[o] * W2[o*16+p];
        hb[p] = sinf(freq[p] * acc);
    }
#pragma unroll
    for (int q = 0; q < 16; ++q) {
        float acc = b3[q];
#pragma unroll
        for (int o = 0; o < 16; ++o) acc += hb[o] * W3[o*16+q];
        h3[j*16+q] = sinf(freq[q] * acc);
    }
}

// ---------------- 4-stage (radix-16-as-radix-2^4) register butterflies ----------------
struct TwSet { float2 t[8]; float2 u[4]; float2 v0, v1, wa; };
static __device__ __forceinline__ TwSet mktw(float2 wd){
    TwSet S;
    const float C1x=0.9238795325112867f, C1y=-0.3826834323650898f;  // e^{-i pi/8}
    const float C2x=0.7071067811865476f, C2y=-0.7071067811865476f;  // e^{-i pi/4}
    const float C3x=0.3826834323650898f, C3y=-0.9238795325112867f;  // e^{-i 3pi/8}
    float2 wc = cmul(wd,wd), wb = cmul(wc,wc);
    S.wa = cmul(wb,wb);
    S.t[0]=wd;
    S.t[1]=f2(wd.x*C1x-wd.y*C1y, wd.x*C1y+wd.y*C1x);
    S.t[2]=f2(wd.x*C2x-wd.y*C2y, wd.x*C2y+wd.y*C2x);
    S.t[3]=f2(wd.x*C3x-wd.y*C3y, wd.x*C3y+wd.y*C3x);
    S.t[4]=mul_mi(S.t[0]); S.t[5]=mul_mi(S.t[1]); S.t[6]=mul_mi(S.t[2]); S.t[7]=mul_mi(S.t[3]);
    S.u[0]=wc;
    S.u[1]=f2(wc.x*C2x-wc.y*C2y, wc.x*C2y+wc.y*C2x);
    S.u[2]=mul_mi(S.u[0]); S.u[3]=mul_mi(S.u[1]);
    S.v0=wb; S.v1=mul_mi(wb);
    return S;
}
// DIF (forward), stages m_lo+3 .. m_lo descending; r[k] = c[base + k*2^m_lo]
static __device__ __forceinline__ void dif4(float2 r[16], float2 wd){
    TwSet S = mktw(wd);
#pragma unroll
    for(int k=0;k<8;++k){ float2 u=r[k], v=r[k+8]; r[k]=cadd(u,v); r[k+8]=cmul(csub(u,v), S.t[k]); }
#pragma unroll
    for(int b=0;b<16;b+=8)
#pragma unroll
      for(int k=0;k<4;++k){ float2 u=r[b+k], v=r[b+k+4]; r[b+k]=cadd(u,v); r[b+k+4]=cmul(csub(u,v), S.u[k]); }
#pragma unroll
    for(int b=0;b<16;b+=4){
        { float2 u=r[b],   v=r[b+2]; r[b]  =cadd(u,v); r[b+2]=cmul(csub(u,v), S.v0); }
        { float2 u=r[b+1], v=r[b+3]; r[b+1]=cadd(u,v); r[b+3]=cmul(csub(u,v), S.v1); }
    }
#pragma unroll
    for(int b=0;b<16;b+=2){ float2 u=r[b], v=r[b+1]; r[b]=cadd(u,v); r[b+1]=cmul(csub(u,v), S.wa); }
}
// DIT (inverse), stages m_lo .. m_lo+3 ascending, conjugated twiddles
static __device__ __forceinline__ void dit4(float2 r[16], float2 wd){
    TwSet S = mktw(wd);
#pragma unroll
    for(int b=0;b<16;b+=2){ float2 u=r[b]; float2 t=cmulc(r[b+1], S.wa); r[b]=cadd(u,t); r[b+1]=csub(u,t); }
#pragma unroll
    for(int b=0;b<16;b+=4){
        { float2 u=r[b];   float2 t=cmulc(r[b+2], S.v0); r[b]  =cadd(u,t); r[b+2]=csub(u,t); }
        { float2 u=r[b+1]; float2 t=cmulc(r[b+3], S.v1); r[b+1]=cadd(u,t); r[b+3]=csub(u,t); }
    }
#pragma unroll
    for(int b=0;b<16;b+=8)
#pragma unroll
      for(int k=0;k<4;++k){ float2 u=r[b+k]; float2 t=cmulc(r[b+k+4], S.u[k]); r[b+k]=cadd(u,t); r[b+k+4]=csub(u,t); }
#pragma unroll
    for(int k=0;k<8;++k){ float2 u=r[k]; float2 t=cmulc(r[k+8], S.t[k]); r[k]=cadd(u,t); r[k+8]=csub(u,t); }
}

// aligned pair access (positions p even; swz may flip parity, so select)
static __device__ __forceinline__ void readpair(const float2* cv, int p, float2& e0, float2& e1){
    int sp = swz(p);
    float4 q = *(const float4*)&cv[sp & ~1];
    float2 lo = f2(q.x,q.y), hi = f2(q.z,q.w);
    if (sp & 1) { e0 = hi; e1 = lo; } else { e0 = lo; e1 = hi; }
}
static __device__ __forceinline__ void writepair(float2* cv, int p, float2 e0, float2 e1){
    int sp = swz(p);
    float4 q;
    if (sp & 1) q = make_float4(e1.x,e1.y,e0.x,e0.y);
    else        q = make_float4(e0.x,e0.y,e1.x,e1.y);
    *(float4*)&cv[sp & ~1] = q;
}

static __device__ __forceinline__ float2 getw(const float2* T1, const float2* T2, int k){
    return cmul(T1[k>>6], T2[k&63]);   // e^{-i pi k / 8192}
}
// rfft unpack K[k], K[8192-k] packed as float4 (scaled by 1/16384, +bias*s on real parts)
static __device__ __forceinline__ float4 kpack(float2 Ck, float2 Cm, float2 w, float bds){
    const float s = 1.0f/16384.0f;
    float2 A  = f2(0.5f*(Ck.x+Cm.x), 0.5f*(Ck.y-Cm.y));
    float2 Bc = f2(0.5f*(Ck.x-Cm.x), 0.5f*(Ck.y+Cm.y));
    float2 B  = f2(Bc.y, -Bc.x);
    float2 wB = cmul(w, B);
    return make_float4((A.x+wB.x)*s + bds, (A.y+wB.y)*s,
                       (A.x-wB.x)*s + bds, -((A.y-wB.y)*s));
}
// unpack X via w, multiply with packed K, repack into C'[k], C'[8192-k]
static __device__ __forceinline__ void pwmul(float2 Ck, float2 Cm, float4 Kp, float2 w,
                                             float2& Dk, float2& Dm){
    float2 A  = f2(0.5f*(Ck.x+Cm.x), 0.5f*(Ck.y-Cm.y));
    float2 Bc = f2(0.5f*(Ck.x-Cm.x), 0.5f*(Ck.y+Cm.y));
    float2 B  = f2(Bc.y, -Bc.x);
    float2 wB = cmul(w, B);
    float2 Xk = f2(A.x+wB.x, A.y+wB.y);
    float2 Xm = f2(A.x-wB.x, -(A.y-wB.y));
    float2 Yk = cmul(Xk, f2(Kp.x,Kp.y));
    float2 Ym = cmul(Xm, f2(Kp.z,Kp.w));
    float2 A2 = f2(Yk.x+Ym.x, Yk.y-Ym.y);
    float2 Bt = f2(Yk.x-Ym.x, Yk.y+Ym.y);
    float2 B2 = cmulc(Bt, w);
    Dk = f2(A2.x - B2.y, A2.y + B2.x);
    Dm = f2(A2.x + B2.y, B2.x - A2.y);
}

// LDS: cv 8192 f2 | tab 512 | T1 64 | T2 64  = 8832 f2 = 70656 B  -> 2 blocks/CU
#define SMEM_BYTES (8832 * 8)

// NOTE: arg2 is empirically CUDA-style min-BLOCKS/CU on this hipcc:
// (512,4) produced VGPR_Count=64 (32-wave budget) + 1.8 GB scratch traffic.
// (512,2) -> 16 waves/CU -> 128-VGPR budget, fits the ~115-reg working set.
__global__ __launch_bounds__(NT, 2)
void hyena_conv(const float* __restrict__ h3g, const float* __restrict__ Wout,
                const float* __restrict__ x, const float* __restrict__ bias,
                float* __restrict__ out) {
    extern __shared__ float4 smem4[];
    float2* cv  = (float2*)smem4;       // 8192
    float2* tab = cv + 8192;            // 512: W_8192^p
    float2* T1  = tab + 512;            // 64:  e^{-i pi h/128}
    float2* T2  = T1 + 64;              // 64:  e^{-i pi l/8192}
    const int t = threadIdx.x;
    const int d = blockIdx.x;
    const float PI = 3.14159265358979323846f;

    { float s_,c_; sincosf((PI/4096.0f)*(float)t, &s_, &c_); tab[t] = f2(c_, -s_); }
    if (t < 64)       { float s_,c_; sincosf((PI/128.0f)*(float)t, &s_,&c_); T1[t] = f2(c_,-s_); }
    else if (t < 128) { int l=t-64; float s_,c_; sincosf((PI/8192.0f)*(float)l,&s_,&c_); T2[l] = f2(c_,-s_); }
    __syncthreads();

    const float2 wd1 = tab[t];            // pass stride 512 (stages 12..9 / 9..12)
    const float2 wd2 = tab[(t&31)<<4];    // pass stride 32  (stages 8..5 / 5..8)
    const float2 wd3 = tab[(t&1)<<8];     // pass stride 2   (stages 4..1 / 1..4)
    const int b2 = ((t>>5)<<9) | (t&31);
    const int b3 = ((t>>1)<<5) | (t&1);

    // ---- filter row k_d -> spectrum K (kept in registers), bias folded in ----
    const float dmin = -3.0701134573253941f;   // log(0.01)/1.5
    const float dmax = -15.350567286626971f;   // log(0.01)/0.3
    const float absd = fabsf(dmin + (dmax - dmin) * ((float)d * (1.0f/1023.0f)));
    const float bds = bias[d] * (1.0f/16384.0f);
    float wcol[16];
#pragma unroll
    for (int o = 0; o < 16; ++o) wcol[o] = Wout[o*1024 + d];

    float2 r[16];
#pragma unroll
    for (int k = 0; k < 8; ++k) {
        int e = t + 512*k;                      // packed complex idx; samples 2e, 2e+1
        const float* h0 = h3g + (size_t)(2*e)*16;
        float a0 = 0.f, a1 = 0.f;
#pragma unroll
        for (int o = 0; o < 16; ++o) a0 += h0[o]    * wcol[o];
#pragma unroll
        for (int o = 0; o < 16; ++o) a1 += h0[16+o] * wcol[o];
        float ta = (float)(2*e)   * (1.0f/8191.0f);
        float tb = (float)(2*e+1) * (1.0f/8191.0f);
        r[k] = f2(a0 * __expf(-ta*absd), a1 * __expf(-tb*absd));
    }
#pragma unroll
    for (int k = 8; k < 16; ++k) r[k] = f2(0.f, 0.f);

    dif4(r, wd1);
#pragma unroll
    for (int k = 0; k < 16; ++k) cv[swz(t + 512*k)] = r[k];
    __syncthreads();
#pragma unroll
    for (int k = 0; k < 16; ++k) r[k] = cv[swz(b2 + 32*k)];
    dif4(r, wd2);
#pragma unroll
    for (int k = 0; k < 16; ++k) cv[swz(b2 + 32*k)] = r[k];
    __syncthreads();
#pragma unroll
    for (int k = 0; k < 16; ++k) r[k] = cv[swz(b3 + 2*k)];
    dif4(r, wd3);
#pragma unroll
    for (int k = 0; k < 16; ++k) cv[swz(b3 + 2*k)] = r[k];
    __syncthreads();

    float4 Ka[4], Kb[4];
    float4 K20 = make_float4(0.f,0.f,0.f,0.f);
#pragma unroll
    for (int q = 0; q < 4; ++q) {
        int f = t + 512*q;
        if (f == 0) {
            float2 a0,a1; readpair(cv, 0, a0, a1);
            float2 C0 = cadd(a0,a1), C4 = csub(a0,a1);   // fwd stage 0
            const float s = 1.0f/16384.0f;
            Ka[q] = make_float4((C0.x+C0.y)*s + bds, (C0.x-C0.y)*s + bds, C4.x*s + bds, -C4.y*s);
            Kb[q] = make_float4(0.f,0.f,0.f,0.f);
        } else {
            int g = 4096 - f;
            float2 a0,a1,b0,b1;
            readpair(cv, rev13(f), a0, a1);
            readpair(cv, rev13(g), b0, b1);
            float2 Cf=cadd(a0,a1), Cf4=csub(a0,a1), Cg=cadd(b0,b1), Cg4=csub(b0,b1);
            Ka[q] = kpack(Cf, Cg4, getw(T1,T2,f), bds);
            Kb[q] = kpack(Cg, Cf4, getw(T1,T2,g), bds);
        }
    }
    if (t == 0) {
        float2 b0,b1; readpair(cv, 2, b0, b1);   // rev13(2048) = 2
        K20 = kpack(cadd(b0,b1), csub(b0,b1), getw(T1,T2,2048), bds);
    }
    __syncthreads();

    // ---- batches ----
    for (int b = 0; b < 4; ++b) {
        const float2* xr = (const float2*)(x + ((size_t)b*1024 + d)*SEQ_LEN);
        float2* yr = (float2*)(out + ((size_t)b*1024 + d)*SEQ_LEN);

        // F1: global -> regs, stages 12..9, -> LDS
#pragma unroll
        for (int k = 0; k < 8; ++k) r[k] = xr[t + 512*k];
#pragma unroll
        for (int k = 8; k < 16; ++k) r[k] = f2(0.f,0.f);
        dif4(r, wd1);
#pragma unroll
        for (int k = 0; k < 16; ++k) cv[swz(t + 512*k)] = r[k];
        __syncthreads();
        // F2: stages 8..5
#pragma unroll
        for (int k = 0; k < 16; ++k) r[k] = cv[swz(b2 + 32*k)];
        dif4(r, wd2);
#pragma unroll
        for (int k = 0; k < 16; ++k) cv[swz(b2 + 32*k)] = r[k];
        __syncthreads();
        // F3: stages 4..1
#pragma unroll
        for (int k = 0; k < 16; ++k) r[k] = cv[swz(b3 + 2*k)];
        dif4(r, wd3);
#pragma unroll
        for (int k = 0; k < 16; ++k) cv[swz(b3 + 2*k)] = r[k];
        __syncthreads();

        // FUSED: fwd stage 0 + rfft-unpack * K + repack + inv stage 0
#pragma unroll
        for (int q = 0; q < 4; ++q) {
            int f = t + 512*q;
            if (f == 0) {
                float2 a0,a1; readpair(cv, 0, a0, a1);
                float2 C0 = cadd(a0,a1), C4 = csub(a0,a1);
                float R0 = C0.x + C0.y, RN = C0.x - C0.y;
                float Y0 = R0 * Ka[0].x, YN = RN * Ka[0].y;
                float2 D0 = f2(Y0+YN, Y0-YN);
                float2 Y4 = cmul(f2(C4.x,-C4.y), f2(Ka[0].z, Ka[0].w));
                float2 D4 = f2(2.f*Y4.x, -2.f*Y4.y);
                writepair(cv, 0, cadd(D0,D4), csub(D0,D4));
            } else {
                int g = 4096 - f;
                int p1 = rev13(f), p2 = rev13(g);
                float2 a0,a1,b0,b1;
                readpair(cv, p1, a0, a1);
                readpair(cv, p2, b0, b1);
                float2 Cf=cadd(a0,a1), Cf4=csub(a0,a1), Cg=cadd(b0,b1), Cg4=csub(b0,b1);
                float2 Df,Dg4,Dg,Df4;
                pwmul(Cf, Cg4, Ka[q], getw(T1,T2,f), Df, Dg4);
                pwmul(Cg, Cf4, Kb[q], getw(T1,T2,g), Dg, Df4);
                writepair(cv, p1, cadd(Df,Df4), csub(Df,Df4));
                writepair(cv, p2, cadd(Dg,Dg4), csub(Dg,Dg4));
            }
        }
        if (t == 0) {   // f = 2048 self-paired quad at positions (2,3)
            float2 b0,b1; readpair(cv, 2, b0, b1);
            float2 Ck=cadd(b0,b1), Cm=csub(b0,b1), Dk, Dm;
            pwmul(Ck, Cm, K20, getw(T1,T2,2048), Dk, Dm);
            writepair(cv, 2, cadd(Dk,Dm), csub(Dk,Dm));
        }
        __syncthreads();

        // I2: stages 1..4
#pragma unroll
        for (int k = 0; k < 16; ++k) r[k] = cv[swz(b3 + 2*k)];
        dit4(r, wd3);
#pragma unroll
        for (int k = 0; k < 16; ++k) cv[swz(b3 + 2*k)] = r[k];
        __syncthreads();
        // I3: stages 5..8
#pragma unroll
        for (int k = 0; k < 16; ++k) r[k] = cv[swz(b2 + 32*k)];
        dit4(r, wd2);
#pragma unroll
        for (int k = 0; k < 16; ++k) cv[swz(b2 + 32*k)] = r[k];
        __syncthreads();
        // I4: stages 9..12, write first half straight to global (bias folded into K)
#pragma unroll
        for (int k = 0; k < 16; ++k) r[k] = cv[swz(t + 512*k)];
        dit4(r, wd1);
#pragma unroll
        for (int k = 0; k < 8; ++k) yr[t + 512*k] = r[k];
        __syncthreads();
    }
}

extern "C" void kernel_launch(void* const* d_in, const int* in_sizes, int n_in,
                              void* d_out, int out_size, void* d_ws, size_t ws_size,
                              hipStream_t stream) {
    const float* x    = (const float*)d_in[0];
    const float* z    = (const float*)d_in[2];
    const float* W1   = (const float*)d_in[3];
    const float* b1   = (const float*)d_in[4];
    const float* W2   = (const float*)d_in[5];
    const float* b2   = (const float*)d_in[6];
    const float* W3   = (const float*)d_in[7];
    const float* b3   = (const float*)d_in[8];
    const float* Wout = (const float*)d_in[9];
    const float* freq = (const float*)d_in[10];
    const float* bias = (const float*)d_in[11];
    float* out = (float*)d_out;
    float* h3  = (float*)d_ws;   // 8192*16 floats = 512 KB

    hipLaunchKernelGGL(hyena_mlp, dim3(SEQ_LEN/256), dim3(256), 0, stream,
                       z, W1, b1, W2, b2, W3, b3, freq, h3);

    static bool attr_set = false;
    if (!attr_set) {
        (void)hipFuncSetAttribute((const void*)hyena_conv,
                                  hipFuncAttributeMaxDynamicSharedMemorySize,
                                  SMEM_BYTES);
        attr_set = true;
    }
    hipLaunchKernelGGL(hyena_conv, dim3(1024), dim3(NT), SMEM_BYTES, stream,
                       h3, Wout, x, bias, out);
}